// Round 1
// baseline (4384.462 us; speedup 1.0000x reference)
//
#include <hip/hip_runtime.h>

#define NUM_USER 200000
#define NUM_ITEM 400000
#define NNODES   (NUM_USER + NUM_ITEM)   // 600000
#define D        64
#define NNZ      6000000
#define ND       ((size_t)NNODES * D)    // 38.4e6 elements

// Gather one element of the ego (concatenated) embedding without materializing it.
__device__ __forceinline__ float ego_at(const float* __restrict__ uemb,
                                        const float* __restrict__ iemb,
                                        int node, int d) {
    return (node < NUM_USER) ? uemb[(size_t)node * D + d]
                             : iemb[(size_t)(node - NUM_USER) * D + d];
}

// dst[r,d] += val * ego(c,d)   (first hop: source gathered from the two input arrays)
__global__ void spmm_scatter_ego(const float* __restrict__ vals,
                                 const int* __restrict__ rows,
                                 const int* __restrict__ cols,
                                 const float* __restrict__ uemb,
                                 const float* __restrict__ iemb,
                                 float* __restrict__ dst) {
    long long gid = (long long)blockIdx.x * blockDim.x + threadIdx.x;
    if (gid >= (long long)NNZ * D) return;
    int e = (int)(gid >> 6);
    int d = (int)(gid & 63);
    int r = rows[e];
    int c = cols[e];
    float v = vals[e];
    atomicAdd(dst + (size_t)r * D + d, v * ego_at(uemb, iemb, c, d));
}

// dst[r,d] += val * src[c,d]   (generic hop)
__global__ void spmm_scatter(const float* __restrict__ vals,
                             const int* __restrict__ rows,
                             const int* __restrict__ cols,
                             const float* __restrict__ src,
                             float* __restrict__ dst) {
    long long gid = (long long)blockIdx.x * blockDim.x + threadIdx.x;
    if (gid >= (long long)NNZ * D) return;
    int e = (int)(gid >> 6);
    int d = (int)(gid & 63);
    int r = rows[e];
    int c = cols[e];
    float v = vals[e];
    atomicAdd(dst + (size_t)r * D + d, v * src[(size_t)c * D + d]);
}

// buf[i,d] += ego(i,d)
__global__ void add_ego(float* __restrict__ buf,
                        const float* __restrict__ uemb,
                        const float* __restrict__ iemb) {
    long long gid = (long long)blockIdx.x * blockDim.x + threadIdx.x;
    if (gid >= (long long)ND) return;
    int node = (int)(gid >> 6);
    int d = (int)(gid & 63);
    buf[gid] += ego_at(uemb, iemb, node, d);
}

// out[i,d] = (out[i,d] + ego(i,d)) * 0.25f
__global__ void finalize_mean(float* __restrict__ out,
                              const float* __restrict__ uemb,
                              const float* __restrict__ iemb) {
    long long gid = (long long)blockIdx.x * blockDim.x + threadIdx.x;
    if (gid >= (long long)ND) return;
    int node = (int)(gid >> 6);
    int d = (int)(gid & 63);
    out[gid] = (out[gid] + ego_at(uemb, iemb, node, d)) * 0.25f;
}

extern "C" void kernel_launch(void* const* d_in, const int* in_sizes, int n_in,
                              void* d_out, int out_size, void* d_ws, size_t ws_size,
                              hipStream_t stream) {
    const float* vals = (const float*)d_in[0];
    const float* uemb = (const float*)d_in[1];
    const float* iemb = (const float*)d_in[2];
    const int*   rows = (const int*)d_in[3];        // adj_indices[0]
    const int*   cols = rows + NNZ;                  // adj_indices[1]
    // d_in[4] = gcn_layer (scalar 3 on device); hardcoded to match reference constant.

    float* out = (float*)d_out;   // doubles as Horner buffer X
    float* Y   = (float*)d_ws;    // needs ND*4 = 153.6 MB

    const int BLK = 256;
    const long long edge_threads = (long long)NNZ * D;
    const int edge_blocks = (int)((edge_threads + BLK - 1) / BLK);
    const int node_blocks = (int)((ND + BLK - 1) / BLK);

    // Horner: out = A(e + A(e + A e)); then out = (out + e)/4
    // 1) out = A e
    hipMemsetAsync(out, 0, ND * sizeof(float), stream);
    spmm_scatter_ego<<<edge_blocks, BLK, 0, stream>>>(vals, rows, cols, uemb, iemb, out);
    // 2) out = e + A e
    add_ego<<<node_blocks, BLK, 0, stream>>>(out, uemb, iemb);
    // 3) Y = A(e + A e)
    hipMemsetAsync(Y, 0, ND * sizeof(float), stream);
    spmm_scatter<<<edge_blocks, BLK, 0, stream>>>(vals, rows, cols, out, Y);
    // 4) Y = e + A(e + A e)
    add_ego<<<node_blocks, BLK, 0, stream>>>(Y, uemb, iemb);
    // 5) out = A(Y) = Ae + A^2 e + A^3 e
    hipMemsetAsync(out, 0, ND * sizeof(float), stream);
    spmm_scatter<<<edge_blocks, BLK, 0, stream>>>(vals, rows, cols, Y, out);
    // 6) out = (out + e) / 4
    finalize_mean<<<node_blocks, BLK, 0, stream>>>(out, uemb, iemb);
}

// Round 2
// 2890.302 us; speedup vs baseline: 1.5170x; 1.5170x over previous
//
#include <hip/hip_runtime.h>

#define NUM_USER 200000
#define NUM_ITEM 400000
#define NNODES   (NUM_USER + NUM_ITEM)   // 600000
#define D        64
#define NNZ      6000000
#define ND       ((size_t)NNODES * D)    // 38.4e6 elements
#define SCAN_CHUNK 2048
#define NCHUNKS  ((NNODES + SCAN_CHUNK - 1) / SCAN_CHUNK)  // 293

__device__ __forceinline__ float ego_at(const float* __restrict__ uemb,
                                        const float* __restrict__ iemb,
                                        int node, int d) {
    return (node < NUM_USER) ? uemb[(size_t)node * D + d]
                             : iemb[(size_t)(node - NUM_USER) * D + d];
}

// ---------------- CSR build ----------------

__global__ void k_hist(const int* __restrict__ rows, int* __restrict__ counts) {
    int e = blockIdx.x * blockDim.x + threadIdx.x;
    if (e < NNZ) atomicAdd(&counts[rows[e]], 1);
}

// Per-chunk exclusive scan (2048 elems/block, 256 thr × 8), chunk totals out.
__global__ void k_scanA(const int* __restrict__ counts, int* __restrict__ row_ptr,
                        int* __restrict__ chunk_sums) {
    __shared__ int tsum[256];
    int base = blockIdx.x * SCAN_CHUNK;
    int t = threadIdx.x;
    int local[8];
    int s = 0;
    #pragma unroll
    for (int k = 0; k < 8; ++k) {
        int idx = base + t * 8 + k;
        int v = (idx < NNODES) ? counts[idx] : 0;
        local[k] = s;
        s += v;
    }
    tsum[t] = s;
    __syncthreads();
    for (int off = 1; off < 256; off <<= 1) {
        int v = (t >= off) ? tsum[t - off] : 0;
        __syncthreads();
        tsum[t] += v;
        __syncthreads();
    }
    int thread_excl = (t == 0) ? 0 : tsum[t - 1];
    #pragma unroll
    for (int k = 0; k < 8; ++k) {
        int idx = base + t * 8 + k;
        if (idx < NNODES) row_ptr[idx] = thread_excl + local[k];
    }
    if (t == 255) chunk_sums[blockIdx.x] = tsum[255];
}

// Single-block exclusive scan of chunk sums (NCHUNKS=293 <= 512).
__global__ void k_scanB(int* __restrict__ chunk_sums) {
    __shared__ int sh[512];
    int t = threadIdx.x;
    sh[t] = (t < NCHUNKS) ? chunk_sums[t] : 0;
    __syncthreads();
    for (int off = 1; off < 512; off <<= 1) {
        int v = (t >= off) ? sh[t - off] : 0;
        __syncthreads();
        sh[t] += v;
        __syncthreads();
    }
    if (t < NCHUNKS) chunk_sums[t] = (t == 0) ? 0 : sh[t - 1];
}

__global__ void k_scanC(int* __restrict__ row_ptr, const int* __restrict__ chunk_sums,
                        int* __restrict__ cursor) {
    int idx = blockIdx.x * blockDim.x + threadIdx.x;
    if (idx < NNODES) {
        int v = row_ptr[idx] + chunk_sums[idx / SCAN_CHUNK];
        row_ptr[idx] = v;
        cursor[idx] = v;
    }
    if (idx == 0) row_ptr[NNODES] = NNZ;
}

// Bin edges into row-sorted packed (col, val_bits) pairs.
__global__ void k_bin(const int* __restrict__ rows, const int* __restrict__ cols,
                      const float* __restrict__ vals,
                      int* __restrict__ cursor, int2* __restrict__ edges) {
    int e = blockIdx.x * blockDim.x + threadIdx.x;
    if (e >= NNZ) return;
    int r = rows[e];
    int pos = atomicAdd(&cursor[r], 1);
    edges[pos] = make_int2(cols[e], __float_as_int(vals[e]));
}

// ---------------- pull-style SpMM ----------------
// One wave per destination row; lane = embedding dim.

__global__ void k_pull(const int* __restrict__ row_ptr, const int2* __restrict__ edges,
                       const float* __restrict__ src, float* __restrict__ dst) {
    int wave = (blockIdx.x * blockDim.x + threadIdx.x) >> 6;
    int lane = threadIdx.x & 63;
    if (wave >= NNODES) return;
    int beg = row_ptr[wave];
    int end = row_ptr[wave + 1];
    float acc = 0.f;
    for (int j = beg; j < end; ++j) {
        int2 cv = edges[j];
        acc += __int_as_float(cv.y) * src[((size_t)cv.x << 6) + lane];
    }
    dst[((size_t)wave << 6) + lane] = acc;
}

__global__ void k_pull_ego(const int* __restrict__ row_ptr, const int2* __restrict__ edges,
                           const float* __restrict__ uemb, const float* __restrict__ iemb,
                           float* __restrict__ dst) {
    int wave = (blockIdx.x * blockDim.x + threadIdx.x) >> 6;
    int lane = threadIdx.x & 63;
    if (wave >= NNODES) return;
    int beg = row_ptr[wave];
    int end = row_ptr[wave + 1];
    float acc = 0.f;
    for (int j = beg; j < end; ++j) {
        int2 cv = edges[j];
        acc += __int_as_float(cv.y) * ego_at(uemb, iemb, cv.x, lane);
    }
    dst[((size_t)wave << 6) + lane] = acc;
}

// Y = ego + X
__global__ void k_add_ego_to(const float* __restrict__ X, float* __restrict__ Y,
                             const float* __restrict__ uemb, const float* __restrict__ iemb) {
    long long gid = (long long)blockIdx.x * blockDim.x + threadIdx.x;
    if (gid >= (long long)ND) return;
    int node = (int)(gid >> 6);
    int d = (int)(gid & 63);
    Y[gid] = X[gid] + ego_at(uemb, iemb, node, d);
}

// out = (out + ego) * 0.25
__global__ void k_finalize(float* __restrict__ out,
                           const float* __restrict__ uemb, const float* __restrict__ iemb) {
    long long gid = (long long)blockIdx.x * blockDim.x + threadIdx.x;
    if (gid >= (long long)ND) return;
    int node = (int)(gid >> 6);
    int d = (int)(gid & 63);
    out[gid] = (out[gid] + ego_at(uemb, iemb, node, d)) * 0.25f;
}

// ---------------- fallback (proven round-1 path) ----------------

__global__ void spmm_scatter_ego(const float* __restrict__ vals, const int* __restrict__ rows,
                                 const int* __restrict__ cols, const float* __restrict__ uemb,
                                 const float* __restrict__ iemb, float* __restrict__ dst) {
    long long gid = (long long)blockIdx.x * blockDim.x + threadIdx.x;
    if (gid >= (long long)NNZ * D) return;
    int e = (int)(gid >> 6), d = (int)(gid & 63);
    atomicAdd(dst + (size_t)rows[e] * D + d, vals[e] * ego_at(uemb, iemb, cols[e], d));
}

__global__ void spmm_scatter(const float* __restrict__ vals, const int* __restrict__ rows,
                             const int* __restrict__ cols, const float* __restrict__ src,
                             float* __restrict__ dst) {
    long long gid = (long long)blockIdx.x * blockDim.x + threadIdx.x;
    if (gid >= (long long)NNZ * D) return;
    int e = (int)(gid >> 6), d = (int)(gid & 63);
    atomicAdd(dst + (size_t)rows[e] * D + d, vals[e] * src[(size_t)cols[e] * D + d]);
}

extern "C" void kernel_launch(void* const* d_in, const int* in_sizes, int n_in,
                              void* d_out, int out_size, void* d_ws, size_t ws_size,
                              hipStream_t stream) {
    const float* vals = (const float*)d_in[0];
    const float* uemb = (const float*)d_in[1];
    const float* iemb = (const float*)d_in[2];
    const int*   rows = (const int*)d_in[3];
    const int*   cols = rows + NNZ;

    float* out = (float*)d_out;
    const int BLK = 256;
    const int node_blocks = (int)((ND + BLK - 1) / BLK);

    // ---- workspace layout ----
    size_t off = 0;
    char* ws = (char*)d_ws;
    auto take = [&](size_t bytes) { char* p = ws + off; off += (bytes + 255) & ~(size_t)255; return p; };
    float* Y        = (float*)take(ND * sizeof(float));
    int*   row_ptr  = (int*)take((NNODES + 1) * sizeof(int));
    int*   counts   = (int*)take(NNODES * sizeof(int));   // reused as cursor
    int*   chunks   = (int*)take(512 * sizeof(int));
    int2*  edges    = (int2*)take((size_t)NNZ * sizeof(int2));
    bool csr_ok = (off <= ws_size);

    if (!csr_ok) {
        // fallback: round-1 atomic scatter path (needs only Y)
        const long long et = (long long)NNZ * D;
        const int eb = (int)((et + BLK - 1) / BLK);
        hipMemsetAsync(out, 0, ND * sizeof(float), stream);
        spmm_scatter_ego<<<eb, BLK, 0, stream>>>(vals, rows, cols, uemb, iemb, out);
        k_add_ego_to<<<node_blocks, BLK, 0, stream>>>(out, Y, uemb, iemb);
        hipMemsetAsync(out, 0, ND * sizeof(float), stream);
        spmm_scatter<<<eb, BLK, 0, stream>>>(vals, rows, cols, Y, out);
        k_add_ego_to<<<node_blocks, BLK, 0, stream>>>(out, Y, uemb, iemb);
        hipMemsetAsync(out, 0, ND * sizeof(float), stream);
        spmm_scatter<<<eb, BLK, 0, stream>>>(vals, rows, cols, Y, out);
        k_finalize<<<node_blocks, BLK, 0, stream>>>(out, uemb, iemb);
        return;
    }

    // ---- build CSR (per launch; deterministic) ----
    const int edge_blocks = (NNZ + BLK - 1) / BLK;
    hipMemsetAsync(counts, 0, NNODES * sizeof(int), stream);
    k_hist<<<edge_blocks, BLK, 0, stream>>>(rows, counts);
    k_scanA<<<NCHUNKS, 256, 0, stream>>>(counts, row_ptr, chunks);
    k_scanB<<<1, 512, 0, stream>>>(chunks);
    k_scanC<<<(NNODES + BLK - 1) / BLK, BLK, 0, stream>>>(row_ptr, chunks, counts);
    k_bin<<<edge_blocks, BLK, 0, stream>>>(rows, cols, vals, counts, edges);

    // ---- 3 hops, Horner: out = A(e + A(e + A e)); out = (out + e)/4 ----
    const int pull_blocks = (NNODES + 3) / 4;  // 4 waves (rows) per 256-thr block
    k_pull_ego<<<pull_blocks, BLK, 0, stream>>>(row_ptr, edges, uemb, iemb, out);
    k_add_ego_to<<<node_blocks, BLK, 0, stream>>>(out, Y, uemb, iemb);
    k_pull<<<pull_blocks, BLK, 0, stream>>>(row_ptr, edges, Y, out);
    k_add_ego_to<<<node_blocks, BLK, 0, stream>>>(out, Y, uemb, iemb);
    k_pull<<<pull_blocks, BLK, 0, stream>>>(row_ptr, edges, Y, out);
    k_finalize<<<node_blocks, BLK, 0, stream>>>(out, uemb, iemb);
}

// Round 3
// 1770.253 us; speedup vs baseline: 2.4767x; 1.6327x over previous
//
#include <hip/hip_runtime.h>

#define NUM_USER 200000
#define NUM_ITEM 400000
#define NNODES   (NUM_USER + NUM_ITEM)   // 600000
#define D        64
#define NNZ      6000000
#define ND       ((size_t)NNODES * D)    // 38.4e6 elements
#define SCAN_CHUNK 2048
#define NCHUNKS  ((NNODES + SCAN_CHUNK - 1) / SCAN_CHUNK)  // 293

typedef float f4 __attribute__((ext_vector_type(4)));

// ---------------- CSR build ----------------

__global__ void k_hist(const int* __restrict__ rows, int* __restrict__ counts) {
    int e = blockIdx.x * blockDim.x + threadIdx.x;
    if (e < NNZ) atomicAdd(&counts[rows[e]], 1);
}

__global__ void k_scanA(const int* __restrict__ counts, int* __restrict__ row_ptr,
                        int* __restrict__ chunk_sums) {
    __shared__ int tsum[256];
    int base = blockIdx.x * SCAN_CHUNK;
    int t = threadIdx.x;
    int local[8];
    int s = 0;
    #pragma unroll
    for (int k = 0; k < 8; ++k) {
        int idx = base + t * 8 + k;
        int v = (idx < NNODES) ? counts[idx] : 0;
        local[k] = s;
        s += v;
    }
    tsum[t] = s;
    __syncthreads();
    for (int off = 1; off < 256; off <<= 1) {
        int v = (t >= off) ? tsum[t - off] : 0;
        __syncthreads();
        tsum[t] += v;
        __syncthreads();
    }
    int thread_excl = (t == 0) ? 0 : tsum[t - 1];
    #pragma unroll
    for (int k = 0; k < 8; ++k) {
        int idx = base + t * 8 + k;
        if (idx < NNODES) row_ptr[idx] = thread_excl + local[k];
    }
    if (t == 255) chunk_sums[blockIdx.x] = tsum[255];
}

__global__ void k_scanB(int* __restrict__ chunk_sums) {
    __shared__ int sh[512];
    int t = threadIdx.x;
    sh[t] = (t < NCHUNKS) ? chunk_sums[t] : 0;
    __syncthreads();
    for (int off = 1; off < 512; off <<= 1) {
        int v = (t >= off) ? sh[t - off] : 0;
        __syncthreads();
        sh[t] += v;
        __syncthreads();
    }
    if (t < NCHUNKS) chunk_sums[t] = (t == 0) ? 0 : sh[t - 1];
}

__global__ void k_scanC(int* __restrict__ row_ptr, const int* __restrict__ chunk_sums,
                        int* __restrict__ cursor) {
    int idx = blockIdx.x * blockDim.x + threadIdx.x;
    if (idx < NNODES) {
        int v = row_ptr[idx] + chunk_sums[idx / SCAN_CHUNK];
        row_ptr[idx] = v;
        cursor[idx] = v;
    }
    if (idx == 0) row_ptr[NNODES] = NNZ;
}

__global__ void k_bin(const int* __restrict__ rows, const int* __restrict__ cols,
                      const float* __restrict__ vals,
                      int* __restrict__ cursor, long long* __restrict__ edges) {
    int e = blockIdx.x * blockDim.x + threadIdx.x;
    if (e >= NNZ) return;
    int r = rows[e];
    int pos = atomicAdd(&cursor[r], 1);
    long long packed = ((long long)__float_as_int(vals[e]) << 32) | (unsigned)cols[e];
    edges[pos] = packed;
}

// ---------------- fused pull hop ----------------
// One wave per destination row. 16 lanes x float4 cover D=64; 4 edge-groups
// per wave process 4 edges concurrently (4x memory-level parallelism).
// dst[r] = (sum_j v_j * src[c_j] + ego(r)) * (FINAL ? 0.25 : 1)

template<bool SRC_EGO, bool FINAL>
__global__ void k_hop(const int* __restrict__ row_ptr,
                      const long long* __restrict__ edges,
                      const float* __restrict__ src,
                      const float* __restrict__ uemb,
                      const float* __restrict__ iemb,
                      float* __restrict__ dst) {
    int wid = (blockIdx.x * blockDim.x + threadIdx.x) >> 6;
    if (wid >= NNODES) return;
    int lane = threadIdx.x & 63;
    int g = lane >> 4;       // edge group 0..3
    int l = lane & 15;       // float4 slot within the row
    int beg = row_ptr[wid];
    int end = row_ptr[wid + 1];
    f4 acc = {0.f, 0.f, 0.f, 0.f};
    for (int j = beg + g; j < end; j += 4) {
        long long cv = __builtin_nontemporal_load(&edges[j]);
        int col = (int)(unsigned)(cv & 0xffffffffLL);
        float v = __int_as_float((int)(cv >> 32));
        f4 s;
        if (SRC_EGO) {
            const f4* sp = (col < NUM_USER)
                ? (const f4*)uemb + ((size_t)col << 4)
                : (const f4*)iemb + ((size_t)(col - NUM_USER) << 4);
            s = sp[l];
        } else {
            s = ((const f4*)src)[((size_t)col << 4) + l];
        }
        acc += v * s;
    }
    // reduce the 4 edge-groups
    acc.x += __shfl_xor(acc.x, 16, 64);
    acc.y += __shfl_xor(acc.y, 16, 64);
    acc.z += __shfl_xor(acc.z, 16, 64);
    acc.w += __shfl_xor(acc.w, 16, 64);
    acc.x += __shfl_xor(acc.x, 32, 64);
    acc.y += __shfl_xor(acc.y, 32, 64);
    acc.z += __shfl_xor(acc.z, 32, 64);
    acc.w += __shfl_xor(acc.w, 32, 64);
    if (lane < 16) {
        const f4* ep = (wid < NUM_USER)
            ? (const f4*)uemb + ((size_t)wid << 4)
            : (const f4*)iemb + ((size_t)(wid - NUM_USER) << 4);
        f4 res = acc + ep[l];
        if (FINAL) res *= 0.25f;
        __builtin_nontemporal_store(res, (f4*)dst + ((size_t)wid << 4) + l);
    }
}

extern "C" void kernel_launch(void* const* d_in, const int* in_sizes, int n_in,
                              void* d_out, int out_size, void* d_ws, size_t ws_size,
                              hipStream_t stream) {
    const float* vals = (const float*)d_in[0];
    const float* uemb = (const float*)d_in[1];
    const float* iemb = (const float*)d_in[2];
    const int*   rows = (const int*)d_in[3];
    const int*   cols = rows + NNZ;

    float* out = (float*)d_out;
    const int BLK = 256;

    // ---- workspace layout (proven to fit in round 2) ----
    size_t off = 0;
    char* ws = (char*)d_ws;
    auto take = [&](size_t bytes) { char* p = ws + off; off += (bytes + 255) & ~(size_t)255; return p; };
    float*     Y       = (float*)take(ND * sizeof(float));
    int*       row_ptr = (int*)take((NNODES + 1) * sizeof(int));
    int*       counts  = (int*)take(NNODES * sizeof(int));   // reused as cursor
    int*       chunks  = (int*)take(512 * sizeof(int));
    long long* edges   = (long long*)take((size_t)NNZ * sizeof(long long));

    // ---- build CSR ----
    const int edge_blocks = (NNZ + BLK - 1) / BLK;
    hipMemsetAsync(counts, 0, NNODES * sizeof(int), stream);
    k_hist<<<edge_blocks, BLK, 0, stream>>>(rows, counts);
    k_scanA<<<NCHUNKS, 256, 0, stream>>>(counts, row_ptr, chunks);
    k_scanB<<<1, 512, 0, stream>>>(chunks);
    k_scanC<<<(NNODES + BLK - 1) / BLK, BLK, 0, stream>>>(row_ptr, chunks, counts);
    k_bin<<<edge_blocks, BLK, 0, stream>>>(rows, cols, vals, counts, edges);

    // ---- 3 fused hops (Horner): X1 = Ae+e; X2 = A X1+e; out = (A X2+e)/4 ----
    const int hop_blocks = (NNODES + 3) / 4;   // 4 waves per 256-thread block
    k_hop<true,  false><<<hop_blocks, BLK, 0, stream>>>(row_ptr, edges, nullptr, uemb, iemb, out);
    k_hop<false, false><<<hop_blocks, BLK, 0, stream>>>(row_ptr, edges, out,     uemb, iemb, Y);
    k_hop<false, true ><<<hop_blocks, BLK, 0, stream>>>(row_ptr, edges, Y,       uemb, iemb, out);
}

// Round 4
// 1286.863 us; speedup vs baseline: 3.4071x; 1.3756x over previous
//
#include <hip/hip_runtime.h>
#include <stdint.h>

#define NUM_USER 200000
#define NUM_ITEM 400000
#define NNODES   (NUM_USER + NUM_ITEM)   // 600000
#define D        64
#define NNZ      6000000
#define ND       ((size_t)NNODES * D)    // 38.4e6 elements

#define RPB       512                     // rows per bucket
#define NBUCK     ((NNODES + RPB - 1) / RPB)   // 1172
#define CAP       8192                    // max edges staged per bucket (mean 5119, sigma ~72)
#define CHUNK     16384                   // edges per block in coarse scatter

typedef float f4 __attribute__((ext_vector_type(4)));

// ---------------- CSR build: two-level bucket multisplit ----------------

// Coarse histogram over 1172 buckets.
__global__ void k_coarse_hist(const int* __restrict__ rows, int* __restrict__ bcnt) {
    __shared__ int h[NBUCK];
    for (int i = threadIdx.x; i < NBUCK; i += blockDim.x) h[i] = 0;
    __syncthreads();
    int stride = gridDim.x * blockDim.x;
    for (int e = blockIdx.x * blockDim.x + threadIdx.x; e < NNZ; e += stride)
        atomicAdd(&h[rows[e] >> 9], 1);
    __syncthreads();
    for (int i = threadIdx.x; i < NBUCK; i += blockDim.x)
        if (h[i]) atomicAdd(&bcnt[i], h[i]);
}

// Exclusive scan of 1172 bucket counts (1 block, 1024 thr x 2 elems).
// Produces bucket_base (NBUCK+1) and initializes bucket_cursor.
__global__ void k_bucket_scan(const int* __restrict__ bcnt, int* __restrict__ bbase,
                              int* __restrict__ bcur, int* __restrict__ row_ptr) {
    __shared__ int tsum[1024];
    int t = threadIdx.x;
    int i0 = 2 * t, i1 = 2 * t + 1;
    int c0 = (i0 < NBUCK) ? bcnt[i0] : 0;
    int c1 = (i1 < NBUCK) ? bcnt[i1] : 0;
    tsum[t] = c0 + c1;
    __syncthreads();
    for (int off = 1; off < 1024; off <<= 1) {
        int v = (t >= off) ? tsum[t - off] : 0;
        __syncthreads();
        tsum[t] += v;
        __syncthreads();
    }
    int excl = (t == 0) ? 0 : tsum[t - 1];
    if (i0 < NBUCK) { bbase[i0] = excl;      bcur[i0] = excl; }
    if (i1 < NBUCK) { bbase[i1] = excl + c0; bcur[i1] = excl + c0; }
    if (t == 0) { bbase[NBUCK] = NNZ; row_ptr[NNODES] = NNZ; }
}

// Coarse scatter: pack (val | local_row | col) and append into bucket regions.
// Per-block LDS histogram -> one global reservation per (block, bucket).
__global__ void k_coarse_scatter(const int* __restrict__ rows, const int* __restrict__ cols,
                                 const float* __restrict__ vals, int* __restrict__ bcur,
                                 uint64_t* __restrict__ edges) {
    __shared__ int cnt[NBUCK];
    __shared__ int start[NBUCK];
    int t = threadIdx.x;
    long long base = (long long)blockIdx.x * CHUNK;
    for (int i = t; i < NBUCK; i += blockDim.x) cnt[i] = 0;
    __syncthreads();
    for (int i = t; i < CHUNK; i += blockDim.x) {
        long long e = base + i;
        if (e < NNZ) atomicAdd(&cnt[rows[e] >> 9], 1);
    }
    __syncthreads();
    for (int b = t; b < NBUCK; b += blockDim.x) {
        int c = cnt[b];
        start[b] = c ? atomicAdd(&bcur[b], c) : 0;
    }
    __syncthreads();
    for (int i = t; i < NBUCK; i += blockDim.x) cnt[i] = 0;  // reuse as cursor
    __syncthreads();
    for (int i = t; i < CHUNK; i += blockDim.x) {
        long long e = base + i;
        if (e >= NNZ) continue;
        int r = rows[e];
        int b = r >> 9;
        int pos = start[b] + atomicAdd(&cnt[b], 1);
        uint64_t packed = ((uint64_t)(uint32_t)__float_as_int(vals[e]) << 32)
                        | ((uint64_t)(r & (RPB - 1)) << 20)
                        | (uint32_t)cols[e];
        edges[pos] = packed;
    }
}

// Fine sort: one block per bucket; stage in LDS, 512-entry hist+scan,
// emit row_ptr and row-sorted edges (local_row stripped) in place.
__global__ void k_bucket_sort(const int* __restrict__ bbase, uint64_t* __restrict__ edges,
                              int* __restrict__ row_ptr) {
    __shared__ uint64_t stage[CAP];
    __shared__ int hist[RPB];
    __shared__ int cur[RPB];
    int b = blockIdx.x;
    int t = threadIdx.x;
    int bb = bbase[b];
    int cnt = bbase[b + 1] - bb;
    for (int i = t; i < cnt; i += blockDim.x) stage[i] = edges[bb + i];
    for (int i = t; i < RPB; i += blockDim.x) hist[i] = 0;
    __syncthreads();
    for (int i = t; i < cnt; i += blockDim.x)
        atomicAdd(&hist[(uint32_t)(stage[i] >> 20) & (RPB - 1)], 1);
    __syncthreads();
    // inclusive scan of hist[512] with 512 threads
    for (int off = 1; off < RPB; off <<= 1) {
        int v = (t >= off) ? hist[t - off] : 0;
        __syncthreads();
        hist[t] += v;
        __syncthreads();
    }
    int excl = (t == 0) ? 0 : hist[t - 1];
    long long row = (long long)b * RPB + t;
    if (row < NNODES) row_ptr[row] = bb + excl;
    cur[t] = excl;
    __syncthreads();
    for (int i = t; i < cnt; i += blockDim.x) {
        uint64_t e = stage[i];
        int lr = (uint32_t)(e >> 20) & (RPB - 1);
        int pos = atomicAdd(&cur[lr], 1);
        edges[bb + pos] = (e & 0xFFFFFFFF00000000ull) | (e & 0xFFFFFull);
    }
}

// ---------------- fused pull hop (unchanged from round 3) ----------------
// One wave per destination row. 16 lanes x float4 cover D=64; 4 edge-groups
// per wave give 4x memory-level parallelism.
// dst[r] = (sum_j v_j * src[c_j] + ego(r)) * (FINAL ? 0.25 : 1)

template<bool SRC_EGO, bool FINAL>
__global__ void k_hop(const int* __restrict__ row_ptr,
                      const uint64_t* __restrict__ edges,
                      const float* __restrict__ src,
                      const float* __restrict__ uemb,
                      const float* __restrict__ iemb,
                      float* __restrict__ dst) {
    int wid = (blockIdx.x * blockDim.x + threadIdx.x) >> 6;
    if (wid >= NNODES) return;
    int lane = threadIdx.x & 63;
    int g = lane >> 4;
    int l = lane & 15;
    int beg = row_ptr[wid];
    int end = row_ptr[wid + 1];
    f4 acc = {0.f, 0.f, 0.f, 0.f};
    for (int j = beg + g; j < end; j += 4) {
        uint64_t cv = __builtin_nontemporal_load(&edges[j]);
        int col = (int)(cv & 0xffffffffull);
        float v = __int_as_float((int)(cv >> 32));
        f4 s;
        if (SRC_EGO) {
            const f4* sp = (col < NUM_USER)
                ? (const f4*)uemb + ((size_t)col << 4)
                : (const f4*)iemb + ((size_t)(col - NUM_USER) << 4);
            s = sp[l];
        } else {
            s = ((const f4*)src)[((size_t)col << 4) + l];
        }
        acc += v * s;
    }
    acc.x += __shfl_xor(acc.x, 16, 64);
    acc.y += __shfl_xor(acc.y, 16, 64);
    acc.z += __shfl_xor(acc.z, 16, 64);
    acc.w += __shfl_xor(acc.w, 16, 64);
    acc.x += __shfl_xor(acc.x, 32, 64);
    acc.y += __shfl_xor(acc.y, 32, 64);
    acc.z += __shfl_xor(acc.z, 32, 64);
    acc.w += __shfl_xor(acc.w, 32, 64);
    if (lane < 16) {
        const f4* ep = (wid < NUM_USER)
            ? (const f4*)uemb + ((size_t)wid << 4)
            : (const f4*)iemb + ((size_t)(wid - NUM_USER) << 4);
        f4 res = acc + ep[l];
        if (FINAL) res *= 0.25f;
        __builtin_nontemporal_store(res, (f4*)dst + ((size_t)wid << 4) + l);
    }
}

extern "C" void kernel_launch(void* const* d_in, const int* in_sizes, int n_in,
                              void* d_out, int out_size, void* d_ws, size_t ws_size,
                              hipStream_t stream) {
    const float* vals = (const float*)d_in[0];
    const float* uemb = (const float*)d_in[1];
    const float* iemb = (const float*)d_in[2];
    const int*   rows = (const int*)d_in[3];
    const int*   cols = rows + NNZ;

    float* out = (float*)d_out;

    // ---- workspace layout (~204.5 MB; round-2 layout of ~206 MB fit) ----
    size_t off = 0;
    char* ws = (char*)d_ws;
    auto take = [&](size_t bytes) { char* p = ws + off; off += (bytes + 255) & ~(size_t)255; return p; };
    float*    Y       = (float*)take(ND * sizeof(float));
    int*      row_ptr = (int*)take((NNODES + 1) * sizeof(int));
    int*      bcnt    = (int*)take(NBUCK * sizeof(int));
    int*      bbase   = (int*)take((NBUCK + 1) * sizeof(int));
    int*      bcur    = (int*)take(NBUCK * sizeof(int));
    uint64_t* edges   = (uint64_t*)take((size_t)NNZ * sizeof(uint64_t));
    (void)ws_size;

    // ---- build row-sorted edge list ----
    hipMemsetAsync(bcnt, 0, NBUCK * sizeof(int), stream);
    k_coarse_hist<<<512, 512, 0, stream>>>(rows, bcnt);
    k_bucket_scan<<<1, 1024, 0, stream>>>(bcnt, bbase, bcur, row_ptr);
    k_coarse_scatter<<<(NNZ + CHUNK - 1) / CHUNK, 512, 0, stream>>>(rows, cols, vals, bcur, edges);
    k_bucket_sort<<<NBUCK, RPB, 0, stream>>>(bbase, edges, row_ptr);

    // ---- 3 fused hops (Horner): X1 = Ae+e; X2 = A X1+e; out = (A X2+e)/4 ----
    const int hop_blocks = (NNODES + 3) / 4;   // 4 waves per 256-thread block
    k_hop<true,  false><<<hop_blocks, 256, 0, stream>>>(row_ptr, edges, nullptr, uemb, iemb, out);
    k_hop<false, false><<<hop_blocks, 256, 0, stream>>>(row_ptr, edges, out,     uemb, iemb, Y);
    k_hop<false, true ><<<hop_blocks, 256, 0, stream>>>(row_ptr, edges, Y,       uemb, iemb, out);
}

// Round 6
// 1081.001 us; speedup vs baseline: 4.0559x; 1.1904x over previous
//
#include <hip/hip_runtime.h>
#include <stdint.h>

#define NUM_USER 200000
#define NUM_ITEM 400000
#define NNODES   (NUM_USER + NUM_ITEM)   // 600000
#define D        64
#define NNZ      6000000
#define ND       ((size_t)NNODES * D)    // 38.4e6 elements

#define RPB       512                     // rows per bucket
#define NBUCK     ((NNODES + RPB - 1) / RPB)   // 1172
#define CAP       8192                    // max edges staged per bucket (mean 5119)
#define CHUNK     16384                   // edges per block in coarse scatter

typedef float    f4 __attribute__((ext_vector_type(4)));
typedef uint32_t u4 __attribute__((ext_vector_type(4)));

// ---- bf16 helpers (RNE) ----
__device__ __forceinline__ uint32_t bfr(float f) {
    uint32_t u = __float_as_uint(f);
    return (u + 0x7FFFu + ((u >> 16) & 1u)) >> 16;
}
__device__ __forceinline__ uint32_t pack2(float lo, float hi) {
    return (bfr(hi) << 16) | bfr(lo);
}
__device__ __forceinline__ float bl(uint32_t u) { return __uint_as_float(u << 16); }
__device__ __forceinline__ float bh(uint32_t u) { return __uint_as_float(u & 0xFFFF0000u); }

// ---------------- ego -> bf16 table (one pass) ----------------
// tid handles 8 consecutive floats of the concatenated [NNODES][64] table.
__global__ void k_cvt(const float* __restrict__ uemb, const float* __restrict__ iemb,
                      u4* __restrict__ ego_bf) {
    long long tid = (long long)blockIdx.x * blockDim.x + threadIdx.x;
    if (tid >= (long long)(ND / 8)) return;
    int node = (int)(tid >> 3);
    int seg = (int)(tid & 7);
    const f4* src = (node < NUM_USER)
        ? (const f4*)uemb + ((size_t)node << 4) + seg * 2
        : (const f4*)iemb + ((size_t)(node - NUM_USER) << 4) + seg * 2;
    f4 a = src[0], b = src[1];
    u4 o;
    o.x = pack2(a.x, a.y); o.y = pack2(a.z, a.w);
    o.z = pack2(b.x, b.y); o.w = pack2(b.z, b.w);
    ego_bf[tid] = o;
}

// ---------------- CSR build: two-level bucket multisplit ----------------

__global__ void k_coarse_hist(const int* __restrict__ rows, int* __restrict__ bcnt) {
    __shared__ int h[NBUCK];
    for (int i = threadIdx.x; i < NBUCK; i += blockDim.x) h[i] = 0;
    __syncthreads();
    int stride = gridDim.x * blockDim.x;
    for (int e = blockIdx.x * blockDim.x + threadIdx.x; e < NNZ; e += stride)
        atomicAdd(&h[rows[e] >> 9], 1);
    __syncthreads();
    for (int i = threadIdx.x; i < NBUCK; i += blockDim.x)
        if (h[i]) atomicAdd(&bcnt[i], h[i]);
}

__global__ void k_bucket_scan(const int* __restrict__ bcnt, int* __restrict__ bbase,
                              int* __restrict__ bcur, int* __restrict__ row_ptr) {
    __shared__ int tsum[1024];
    int t = threadIdx.x;
    int i0 = 2 * t, i1 = 2 * t + 1;
    int c0 = (i0 < NBUCK) ? bcnt[i0] : 0;
    int c1 = (i1 < NBUCK) ? bcnt[i1] : 0;
    tsum[t] = c0 + c1;
    __syncthreads();
    for (int off = 1; off < 1024; off <<= 1) {
        int v = (t >= off) ? tsum[t - off] : 0;
        __syncthreads();
        tsum[t] += v;
        __syncthreads();
    }
    int excl = (t == 0) ? 0 : tsum[t - 1];
    if (i0 < NBUCK) { bbase[i0] = excl;      bcur[i0] = excl; }
    if (i1 < NBUCK) { bbase[i1] = excl + c0; bcur[i1] = excl + c0; }
    if (t == 0) { bbase[NBUCK] = NNZ; row_ptr[NNODES] = NNZ; }
}

__global__ void k_coarse_scatter(const int* __restrict__ rows, const int* __restrict__ cols,
                                 const float* __restrict__ vals, int* __restrict__ bcur,
                                 uint64_t* __restrict__ edges) {
    __shared__ int cnt[NBUCK];
    __shared__ int start[NBUCK];
    int t = threadIdx.x;
    long long base = (long long)blockIdx.x * CHUNK;
    for (int i = t; i < NBUCK; i += blockDim.x) cnt[i] = 0;
    __syncthreads();
    for (int i = t; i < CHUNK; i += blockDim.x) {
        long long e = base + i;
        if (e < NNZ) atomicAdd(&cnt[rows[e] >> 9], 1);
    }
    __syncthreads();
    for (int b = t; b < NBUCK; b += blockDim.x) {
        int c = cnt[b];
        start[b] = c ? atomicAdd(&bcur[b], c) : 0;
    }
    __syncthreads();
    for (int i = t; i < NBUCK; i += blockDim.x) cnt[i] = 0;  // reuse as cursor
    __syncthreads();
    for (int i = t; i < CHUNK; i += blockDim.x) {
        long long e = base + i;
        if (e >= NNZ) continue;
        int r = rows[e];
        int b = r >> 9;
        int pos = start[b] + atomicAdd(&cnt[b], 1);
        uint64_t packed = ((uint64_t)(uint32_t)__float_as_int(vals[e]) << 32)
                        | ((uint64_t)(r & (RPB - 1)) << 20)
                        | (uint32_t)cols[e];
        edges[pos] = packed;
    }
}

__global__ void k_bucket_sort(const int* __restrict__ bbase, uint64_t* __restrict__ edges,
                              int* __restrict__ row_ptr) {
    __shared__ uint64_t stage[CAP];
    __shared__ int hist[RPB];
    __shared__ int cur[RPB];
    int b = blockIdx.x;
    int t = threadIdx.x;
    int bb = bbase[b];
    int cnt = bbase[b + 1] - bb;
    for (int i = t; i < cnt; i += blockDim.x) stage[i] = edges[bb + i];
    for (int i = t; i < RPB; i += blockDim.x) hist[i] = 0;
    __syncthreads();
    for (int i = t; i < cnt; i += blockDim.x)
        atomicAdd(&hist[(uint32_t)(stage[i] >> 20) & (RPB - 1)], 1);
    __syncthreads();
    for (int off = 1; off < RPB; off <<= 1) {
        int v = (t >= off) ? hist[t - off] : 0;
        __syncthreads();
        hist[t] += v;
        __syncthreads();
    }
    int excl = (t == 0) ? 0 : hist[t - 1];
    long long row = (long long)b * RPB + t;
    if (row < NNODES) row_ptr[row] = bb + excl;
    cur[t] = excl;
    __syncthreads();
    for (int i = t; i < cnt; i += blockDim.x) {
        uint64_t e = stage[i];
        int lr = (uint32_t)(e >> 20) & (RPB - 1);
        int pos = atomicAdd(&cur[lr], 1);
        edges[bb + pos] = (e & 0xFFFFFFFF00000000ull) | (e & 0xFFFFFull);
    }
}

// ---------------- fused pull hop, bf16 gather ----------------
// One wave per destination row. 8 lanes x bf16x8 (16B) cover D=64; 8 edge-groups
// per wave give 8x memory-level parallelism.
// dst[r] = (sum_j v_j * src_bf[c_j] + ego_fp32(r)) * (FINAL ? 0.25 : 1)
// FINAL: dst is fp32 [NNODES][64]; else dst is bf16 table (u4 rows).

template<bool FINAL>
__global__ void k_hop(const int* __restrict__ row_ptr,
                      const uint64_t* __restrict__ edges,
                      const u4* __restrict__ src_bf,
                      const float* __restrict__ uemb,
                      const float* __restrict__ iemb,
                      void* __restrict__ dst) {
    int wid = (blockIdx.x * blockDim.x + threadIdx.x) >> 6;
    if (wid >= NNODES) return;
    int lane = threadIdx.x & 63;
    int g = lane >> 3;   // edge group 0..7
    int l = lane & 7;    // 16B slot within the 128B bf16 row
    int beg = row_ptr[wid];
    int end = row_ptr[wid + 1];
    float acc[8];
    #pragma unroll
    for (int k = 0; k < 8; ++k) acc[k] = 0.f;
    for (int j = beg + g; j < end; j += 8) {
        uint64_t cv = __builtin_nontemporal_load(&edges[j]);
        int col = (int)((uint32_t)cv & 0xFFFFFu);
        float v = __int_as_float((int)(cv >> 32));
        u4 s = src_bf[((size_t)col << 3) + l];
        acc[0] += v * bl(s.x); acc[1] += v * bh(s.x);
        acc[2] += v * bl(s.y); acc[3] += v * bh(s.y);
        acc[4] += v * bl(s.z); acc[5] += v * bh(s.z);
        acc[6] += v * bl(s.w); acc[7] += v * bh(s.w);
    }
    #pragma unroll
    for (int k = 0; k < 8; ++k) {
        acc[k] += __shfl_xor(acc[k], 8, 64);
        acc[k] += __shfl_xor(acc[k], 16, 64);
        acc[k] += __shfl_xor(acc[k], 32, 64);
    }
    if (lane < 8) {
        const f4* ep = (wid < NUM_USER)
            ? (const f4*)uemb + ((size_t)wid << 4) + l * 2
            : (const f4*)iemb + ((size_t)(wid - NUM_USER) << 4) + l * 2;
        f4 e0 = ep[0], e1 = ep[1];
        float r0 = acc[0] + e0.x, r1 = acc[1] + e0.y;
        float r2 = acc[2] + e0.z, r3 = acc[3] + e0.w;
        float r4 = acc[4] + e1.x, r5 = acc[5] + e1.y;
        float r6 = acc[6] + e1.z, r7 = acc[7] + e1.w;
        if (FINAL) {
            f4 o0 = {r0 * 0.25f, r1 * 0.25f, r2 * 0.25f, r3 * 0.25f};
            f4 o1 = {r4 * 0.25f, r5 * 0.25f, r6 * 0.25f, r7 * 0.25f};
            f4* dp = (f4*)dst + ((size_t)wid << 4) + l * 2;
            __builtin_nontemporal_store(o0, dp);
            __builtin_nontemporal_store(o1, dp + 1);
        } else {
            u4 o;
            o.x = pack2(r0, r1); o.y = pack2(r2, r3);
            o.z = pack2(r4, r5); o.w = pack2(r6, r7);
            __builtin_nontemporal_store(o, (u4*)dst + ((size_t)wid << 3) + l);
        }
    }
}

extern "C" void kernel_launch(void* const* d_in, const int* in_sizes, int n_in,
                              void* d_out, int out_size, void* d_ws, size_t ws_size,
                              hipStream_t stream) {
    const float* vals = (const float*)d_in[0];
    const float* uemb = (const float*)d_in[1];
    const float* iemb = (const float*)d_in[2];
    const int*   rows = (const int*)d_in[3];
    const int*   cols = rows + NNZ;

    float* out = (float*)d_out;

    // ---- workspace layout (~204.2 MB; round-2's ~206.5 MB fit) ----
    size_t off = 0;
    char* ws = (char*)d_ws;
    auto take = [&](size_t bytes) { char* p = ws + off; off += (bytes + 255) & ~(size_t)255; return p; };
    u4*       ego_bf  = (u4*)take((ND / 8) * sizeof(u4));   // 76.8 MB; reused as X2
    u4*       X1      = (u4*)take((ND / 8) * sizeof(u4));   // 76.8 MB
    int*      row_ptr = (int*)take((NNODES + 1) * sizeof(int));
    int*      bcnt    = (int*)take(NBUCK * sizeof(int));
    int*      bbase   = (int*)take((NBUCK + 1) * sizeof(int));
    int*      bcur    = (int*)take(NBUCK * sizeof(int));
    uint64_t* edges   = (uint64_t*)take((size_t)NNZ * sizeof(uint64_t));  // 48 MB
    (void)ws_size;

    // ---- ego -> bf16 table ----
    const long long cvt_threads = ND / 8;
    k_cvt<<<(int)((cvt_threads + 255) / 256), 256, 0, stream>>>(uemb, iemb, ego_bf);

    // ---- build row-sorted edge list ----
    hipMemsetAsync(bcnt, 0, NBUCK * sizeof(int), stream);
    k_coarse_hist<<<512, 512, 0, stream>>>(rows, bcnt);
    k_bucket_scan<<<1, 1024, 0, stream>>>(bcnt, bbase, bcur, row_ptr);
    k_coarse_scatter<<<(NNZ + CHUNK - 1) / CHUNK, 512, 0, stream>>>(rows, cols, vals, bcur, edges);
    k_bucket_sort<<<NBUCK, RPB, 0, stream>>>(bbase, edges, row_ptr);

    // ---- 3 fused hops (Horner): X1 = Ae+e; X2 = A X1+e; out = (A X2+e)/4 ----
    const int hop_blocks = (NNODES + 3) / 4;   // 4 waves per 256-thread block
    k_hop<false><<<hop_blocks, 256, 0, stream>>>(row_ptr, edges, ego_bf, uemb, iemb, X1);
    k_hop<false><<<hop_blocks, 256, 0, stream>>>(row_ptr, edges, X1,     uemb, iemb, ego_bf);
    k_hop<true ><<<hop_blocks, 256, 0, stream>>>(row_ptr, edges, ego_bf, uemb, iemb, out);
}

// Round 7
// 870.517 us; speedup vs baseline: 5.0366x; 1.2418x over previous
//
#include <hip/hip_runtime.h>
#include <stdint.h>

#define NUM_USER 200000
#define NUM_ITEM 400000
#define NNODES   (NUM_USER + NUM_ITEM)   // 600000
#define D        64
#define NNZ      6000000
#define ND       ((size_t)NNODES * D)    // 38.4e6 elements

#define RPB       512                     // rows per bucket
#define NBUCK     ((NNODES + RPB - 1) / RPB)   // 1172
#define CAP       8192                    // max edges staged per bucket (mean 5119)
#define CHUNK     16384                   // edges per block in coarse scatter

typedef float    f4 __attribute__((ext_vector_type(4)));
typedef uint32_t u4 __attribute__((ext_vector_type(4)));

// ---- bf16 helpers (RNE) ----
__device__ __forceinline__ uint32_t bfr(float f) {
    uint32_t u = __float_as_uint(f);
    return (u + 0x7FFFu + ((u >> 16) & 1u)) >> 16;
}
__device__ __forceinline__ uint32_t pack2(float lo, float hi) {
    return (bfr(hi) << 16) | bfr(lo);
}
__device__ __forceinline__ float bl(uint32_t u) { return __uint_as_float(u << 16); }
__device__ __forceinline__ float bh(uint32_t u) { return __uint_as_float(u & 0xFFFF0000u); }

// ---------------- ego -> bf16 table (one pass) ----------------
__global__ void k_cvt(const float* __restrict__ uemb, const float* __restrict__ iemb,
                      u4* __restrict__ ego_bf) {
    long long tid = (long long)blockIdx.x * blockDim.x + threadIdx.x;
    if (tid >= (long long)(ND / 8)) return;
    int node = (int)(tid >> 3);
    int seg = (int)(tid & 7);
    const f4* src = (node < NUM_USER)
        ? (const f4*)uemb + ((size_t)node << 4) + seg * 2
        : (const f4*)iemb + ((size_t)(node - NUM_USER) << 4) + seg * 2;
    f4 a = src[0], b = src[1];
    u4 o;
    o.x = pack2(a.x, a.y); o.y = pack2(a.z, a.w);
    o.z = pack2(b.x, b.y); o.w = pack2(b.z, b.w);
    ego_bf[tid] = o;
}

// ---------------- CSR build: two-level bucket multisplit ----------------

__global__ void k_coarse_hist(const int* __restrict__ rows, int* __restrict__ bcnt) {
    __shared__ int h[NBUCK];
    for (int i = threadIdx.x; i < NBUCK; i += blockDim.x) h[i] = 0;
    __syncthreads();
    int stride = gridDim.x * blockDim.x;
    for (int e = blockIdx.x * blockDim.x + threadIdx.x; e < NNZ; e += stride)
        atomicAdd(&h[rows[e] >> 9], 1);
    __syncthreads();
    for (int i = threadIdx.x; i < NBUCK; i += blockDim.x)
        if (h[i]) atomicAdd(&bcnt[i], h[i]);
}

__global__ void k_bucket_scan(const int* __restrict__ bcnt, int* __restrict__ bbase,
                              int* __restrict__ bcur, int* __restrict__ row_ptr) {
    __shared__ int tsum[1024];
    int t = threadIdx.x;
    int i0 = 2 * t, i1 = 2 * t + 1;
    int c0 = (i0 < NBUCK) ? bcnt[i0] : 0;
    int c1 = (i1 < NBUCK) ? bcnt[i1] : 0;
    tsum[t] = c0 + c1;
    __syncthreads();
    for (int off = 1; off < 1024; off <<= 1) {
        int v = (t >= off) ? tsum[t - off] : 0;
        __syncthreads();
        tsum[t] += v;
        __syncthreads();
    }
    int excl = (t == 0) ? 0 : tsum[t - 1];
    if (i0 < NBUCK) { bbase[i0] = excl;      bcur[i0] = excl; }
    if (i1 < NBUCK) { bbase[i1] = excl + c0; bcur[i1] = excl + c0; }
    if (t == 0) { bbase[NBUCK] = NNZ; row_ptr[NNODES] = NNZ; }
}

__global__ void k_coarse_scatter(const int* __restrict__ rows, const int* __restrict__ cols,
                                 const float* __restrict__ vals, int* __restrict__ bcur,
                                 uint64_t* __restrict__ edges) {
    __shared__ int cnt[NBUCK];
    __shared__ int start[NBUCK];
    int t = threadIdx.x;
    long long base = (long long)blockIdx.x * CHUNK;
    for (int i = t; i < NBUCK; i += blockDim.x) cnt[i] = 0;
    __syncthreads();
    for (int i = t; i < CHUNK; i += blockDim.x) {
        long long e = base + i;
        if (e < NNZ) atomicAdd(&cnt[rows[e] >> 9], 1);
    }
    __syncthreads();
    for (int b = t; b < NBUCK; b += blockDim.x) {
        int c = cnt[b];
        start[b] = c ? atomicAdd(&bcur[b], c) : 0;
    }
    __syncthreads();
    for (int i = t; i < NBUCK; i += blockDim.x) cnt[i] = 0;  // reuse as cursor
    __syncthreads();
    for (int i = t; i < CHUNK; i += blockDim.x) {
        long long e = base + i;
        if (e >= NNZ) continue;
        int r = rows[e];
        int b = r >> 9;
        int pos = start[b] + atomicAdd(&cnt[b], 1);
        uint64_t packed = ((uint64_t)(uint32_t)__float_as_int(vals[e]) << 32)
                        | ((uint64_t)(r & (RPB - 1)) << 20)
                        | (uint32_t)cols[e];
        edges[pos] = packed;
    }
}

__global__ void k_bucket_sort(const int* __restrict__ bbase, uint64_t* __restrict__ edges,
                              int* __restrict__ row_ptr) {
    __shared__ uint64_t stage[CAP];
    __shared__ int hist[RPB];
    __shared__ int cur[RPB];
    int b = blockIdx.x;
    int t = threadIdx.x;
    int bb = bbase[b];
    int cnt = bbase[b + 1] - bb;
    for (int i = t; i < cnt; i += blockDim.x) stage[i] = edges[bb + i];
    for (int i = t; i < RPB; i += blockDim.x) hist[i] = 0;
    __syncthreads();
    for (int i = t; i < cnt; i += blockDim.x)
        atomicAdd(&hist[(uint32_t)(stage[i] >> 20) & (RPB - 1)], 1);
    __syncthreads();
    for (int off = 1; off < RPB; off <<= 1) {
        int v = (t >= off) ? hist[t - off] : 0;
        __syncthreads();
        hist[t] += v;
        __syncthreads();
    }
    int excl = (t == 0) ? 0 : hist[t - 1];
    long long row = (long long)b * RPB + t;
    if (row < NNODES) row_ptr[row] = bb + excl;
    cur[t] = excl;
    __syncthreads();
    for (int i = t; i < cnt; i += blockDim.x) {
        uint64_t e = stage[i];
        int lr = (uint32_t)(e >> 20) & (RPB - 1);
        int pos = atomicAdd(&cur[lr], 1);
        edges[bb + pos] = (e & 0xFFFFFFFF00000000ull) | (e & 0xFFFFFull);
    }
}

// ---------------- fused pull hop: 8 rows per wave, group-per-row ----------------
// lane = (g=row-in-wave: lane>>3, l=16B slot: lane&7). Each 8-lane group walks
// its own row's edge list (no cross-lane reduction); epilogue/store are
// full-wave coalesced (8 consecutive rows = 2KB contiguous).
// EPI: 1 = read +ego from bf16 table; 0 = read +ego from fp32 inputs (nt).
// dst[r] = (sum_j v_j * src_bf[c_j] + ego(r)) * (FINAL ? 0.25 : 1)

template<int EPI, bool FINAL>
__global__ void k_hop(const int* __restrict__ row_ptr,
                      const uint64_t* __restrict__ edges,
                      const u4* __restrict__ src_bf,
                      const u4* __restrict__ ego_bf,
                      const float* __restrict__ uemb,
                      const float* __restrict__ iemb,
                      void* __restrict__ dst) {
    int wave = (blockIdx.x * blockDim.x + threadIdx.x) >> 6;
    int lane = threadIdx.x & 63;
    int g = lane >> 3;   // row within wave's 8
    int l = lane & 7;    // 16B slot within 128B bf16 row
    int r = wave * 8 + g;
    bool rv = (r < NNODES);
    int beg = rv ? row_ptr[r] : 0;
    int end = rv ? row_ptr[r + 1] : 0;
    float acc[8];
    #pragma unroll
    for (int k = 0; k < 8; ++k) acc[k] = 0.f;
    for (int j = beg; ; ++j) {
        bool act = (j < end);
        if (!__any(act)) break;
        if (act) {
            uint64_t cv = __builtin_nontemporal_load(&edges[j]);
            int col = (int)((uint32_t)cv & 0xFFFFFu);
            float v = __int_as_float((int)(cv >> 32));
            u4 s = src_bf[((size_t)col << 3) + l];
            acc[0] += v * bl(s.x); acc[1] += v * bh(s.x);
            acc[2] += v * bl(s.y); acc[3] += v * bh(s.y);
            acc[4] += v * bl(s.z); acc[5] += v * bh(s.z);
            acc[6] += v * bl(s.w); acc[7] += v * bh(s.w);
        }
    }
    if (!rv) return;
    float e[8];
    if (EPI == 1) {
        u4 eg = ego_bf[((size_t)r << 3) + l];
        e[0] = bl(eg.x); e[1] = bh(eg.x); e[2] = bl(eg.y); e[3] = bh(eg.y);
        e[4] = bl(eg.z); e[5] = bh(eg.z); e[6] = bl(eg.w); e[7] = bh(eg.w);
    } else {
        const f4* ep = (r < NUM_USER)
            ? (const f4*)uemb + ((size_t)r << 4) + l * 2
            : (const f4*)iemb + ((size_t)(r - NUM_USER) << 4) + l * 2;
        f4 e0 = __builtin_nontemporal_load(ep);
        f4 e1 = __builtin_nontemporal_load(ep + 1);
        e[0] = e0.x; e[1] = e0.y; e[2] = e0.z; e[3] = e0.w;
        e[4] = e1.x; e[5] = e1.y; e[6] = e1.z; e[7] = e1.w;
    }
    #pragma unroll
    for (int k = 0; k < 8; ++k) acc[k] += e[k];
    if (FINAL) {
        f4 o0 = {acc[0] * 0.25f, acc[1] * 0.25f, acc[2] * 0.25f, acc[3] * 0.25f};
        f4 o1 = {acc[4] * 0.25f, acc[5] * 0.25f, acc[6] * 0.25f, acc[7] * 0.25f};
        f4* dp = (f4*)dst + ((size_t)r << 4) + l * 2;
        __builtin_nontemporal_store(o0, dp);
        __builtin_nontemporal_store(o1, dp + 1);
    } else {
        u4 o;
        o.x = pack2(acc[0], acc[1]); o.y = pack2(acc[2], acc[3]);
        o.z = pack2(acc[4], acc[5]); o.w = pack2(acc[6], acc[7]);
        __builtin_nontemporal_store(o, (u4*)dst + ((size_t)r << 3) + l);
    }
}

extern "C" void kernel_launch(void* const* d_in, const int* in_sizes, int n_in,
                              void* d_out, int out_size, void* d_ws, size_t ws_size,
                              hipStream_t stream) {
    const float* vals = (const float*)d_in[0];
    const float* uemb = (const float*)d_in[1];
    const float* iemb = (const float*)d_in[2];
    const int*   rows = (const int*)d_in[3];
    const int*   cols = rows + NNZ;

    float* out = (float*)d_out;

    // ---- workspace layout ----
    size_t off = 0;
    char* ws = (char*)d_ws;
    auto take = [&](size_t bytes) { char* p = ws + off; off += (bytes + 255) & ~(size_t)255; return p; };
    u4*       ego_bf  = (u4*)take((ND / 8) * sizeof(u4));   // 76.8 MB
    u4*       X1      = (u4*)take((ND / 8) * sizeof(u4));   // 76.8 MB
    int*      row_ptr = (int*)take((NNODES + 1) * sizeof(int));
    int*      bcnt    = (int*)take(NBUCK * sizeof(int));
    int*      bbase   = (int*)take((NBUCK + 1) * sizeof(int));
    int*      bcur    = (int*)take(NBUCK * sizeof(int));
    uint64_t* edges   = (uint64_t*)take((size_t)NNZ * sizeof(uint64_t));  // 48 MB
    size_t base_need = off;                                  // ~204.7 MB (proven fit)
    u4*       X2      = (u4*)take((ND / 8) * sizeof(u4));    // +76.8 MB (conditional)
    bool three_buf = (off <= ws_size);
    (void)base_need;

    // ---- ego -> bf16 table ----
    const long long cvt_threads = ND / 8;
    k_cvt<<<(int)((cvt_threads + 255) / 256), 256, 0, stream>>>(uemb, iemb, ego_bf);

    // ---- build row-sorted edge list ----
    hipMemsetAsync(bcnt, 0, NBUCK * sizeof(int), stream);
    k_coarse_hist<<<512, 512, 0, stream>>>(rows, bcnt);
    k_bucket_scan<<<1, 1024, 0, stream>>>(bcnt, bbase, bcur, row_ptr);
    k_coarse_scatter<<<(NNZ + CHUNK - 1) / CHUNK, 512, 0, stream>>>(rows, cols, vals, bcur, edges);
    k_bucket_sort<<<NBUCK, RPB, 0, stream>>>(bbase, edges, row_ptr);

    // ---- 3 fused hops (Horner): X1 = Ae+e; X2 = A X1+e; out = (A X2+e)/4 ----
    const int hop_blocks = (NNODES + 31) / 32;   // 8 rows/wave, 4 waves/block
    if (three_buf) {
        k_hop<1, false><<<hop_blocks, 256, 0, stream>>>(row_ptr, edges, ego_bf, ego_bf, uemb, iemb, X1);
        k_hop<1, false><<<hop_blocks, 256, 0, stream>>>(row_ptr, edges, X1,     ego_bf, uemb, iemb, X2);
        k_hop<1, true ><<<hop_blocks, 256, 0, stream>>>(row_ptr, edges, X2,     ego_bf, uemb, iemb, out);
    } else {
        // 2-buffer fallback: hop2 writes over ego_bf (safe: its epilogue reads fp32),
        // hops 2-3 read +ego from fp32 inputs with nt loads.
        k_hop<1, false><<<hop_blocks, 256, 0, stream>>>(row_ptr, edges, ego_bf, ego_bf, uemb, iemb, X1);
        k_hop<0, false><<<hop_blocks, 256, 0, stream>>>(row_ptr, edges, X1,     nullptr, uemb, iemb, ego_bf);
        k_hop<0, true ><<<hop_blocks, 256, 0, stream>>>(row_ptr, edges, ego_bf, nullptr, uemb, iemb, out);
    }
}

// Round 8
// 732.144 us; speedup vs baseline: 5.9885x; 1.1890x over previous
//
#include <hip/hip_runtime.h>
#include <stdint.h>

#define NUM_USER 200000
#define NUM_ITEM 400000
#define NNODES   (NUM_USER + NUM_ITEM)   // 600000
#define D        64
#define NNZ      6000000
#define ND       ((size_t)NNODES * D)    // 38.4e6 elements

#define RPB       512                     // rows per bucket
#define NBUCK     ((NNODES + RPB - 1) / RPB)   // 1172
#define CAP       8192                    // max edges staged per bucket (mean 5119)
#define CHUNK     16384                   // edges per block in coarse scatter

typedef float    f4 __attribute__((ext_vector_type(4)));
typedef uint32_t u4 __attribute__((ext_vector_type(4)));

// ---- bf16 helpers (RNE) ----
__device__ __forceinline__ uint32_t bfr(float f) {
    uint32_t u = __float_as_uint(f);
    return (u + 0x7FFFu + ((u >> 16) & 1u)) >> 16;
}
__device__ __forceinline__ uint32_t pack2(float lo, float hi) {
    return (bfr(hi) << 16) | bfr(lo);
}
__device__ __forceinline__ float bl(uint32_t u) { return __uint_as_float(u << 16); }
__device__ __forceinline__ float bh(uint32_t u) { return __uint_as_float(u & 0xFFFF0000u); }

// ---------------- ego -> bf16 table (one pass) ----------------
__global__ void k_cvt(const float* __restrict__ uemb, const float* __restrict__ iemb,
                      u4* __restrict__ ego_bf) {
    long long tid = (long long)blockIdx.x * blockDim.x + threadIdx.x;
    if (tid >= (long long)(ND / 8)) return;
    int node = (int)(tid >> 3);
    int seg = (int)(tid & 7);
    const f4* src = (node < NUM_USER)
        ? (const f4*)uemb + ((size_t)node << 4) + seg * 2
        : (const f4*)iemb + ((size_t)(node - NUM_USER) << 4) + seg * 2;
    f4 a = src[0], b = src[1];
    u4 o;
    o.x = pack2(a.x, a.y); o.y = pack2(a.z, a.w);
    o.z = pack2(b.x, b.y); o.w = pack2(b.z, b.w);
    ego_bf[tid] = o;
}

// ---------------- CSR build: two-level bucket multisplit ----------------

__global__ void k_coarse_hist(const int* __restrict__ rows, int* __restrict__ bcnt) {
    __shared__ int h[NBUCK];
    for (int i = threadIdx.x; i < NBUCK; i += blockDim.x) h[i] = 0;
    __syncthreads();
    int stride = gridDim.x * blockDim.x;
    for (int e = blockIdx.x * blockDim.x + threadIdx.x; e < NNZ; e += stride)
        atomicAdd(&h[rows[e] >> 9], 1);
    __syncthreads();
    for (int i = threadIdx.x; i < NBUCK; i += blockDim.x)
        if (h[i]) atomicAdd(&bcnt[i], h[i]);
}

__global__ void k_bucket_scan(const int* __restrict__ bcnt, int* __restrict__ bbase,
                              int* __restrict__ bcur, int* __restrict__ row_ptr) {
    __shared__ int tsum[1024];
    int t = threadIdx.x;
    int i0 = 2 * t, i1 = 2 * t + 1;
    int c0 = (i0 < NBUCK) ? bcnt[i0] : 0;
    int c1 = (i1 < NBUCK) ? bcnt[i1] : 0;
    tsum[t] = c0 + c1;
    __syncthreads();
    for (int off = 1; off < 1024; off <<= 1) {
        int v = (t >= off) ? tsum[t - off] : 0;
        __syncthreads();
        tsum[t] += v;
        __syncthreads();
    }
    int excl = (t == 0) ? 0 : tsum[t - 1];
    if (i0 < NBUCK) { bbase[i0] = excl;      bcur[i0] = excl; }
    if (i1 < NBUCK) { bbase[i1] = excl + c0; bcur[i1] = excl + c0; }
    if (t == 0) { bbase[NBUCK] = NNZ; row_ptr[NNODES] = NNZ; }
}

__global__ void k_coarse_scatter(const int* __restrict__ rows, const int* __restrict__ cols,
                                 const float* __restrict__ vals, int* __restrict__ bcur,
                                 uint64_t* __restrict__ edges) {
    __shared__ int cnt[NBUCK];
    __shared__ int start[NBUCK];
    int t = threadIdx.x;
    long long base = (long long)blockIdx.x * CHUNK;
    for (int i = t; i < NBUCK; i += blockDim.x) cnt[i] = 0;
    __syncthreads();
    for (int i = t; i < CHUNK; i += blockDim.x) {
        long long e = base + i;
        if (e < NNZ) atomicAdd(&cnt[rows[e] >> 9], 1);
    }
    __syncthreads();
    for (int b = t; b < NBUCK; b += blockDim.x) {
        int c = cnt[b];
        start[b] = c ? atomicAdd(&bcur[b], c) : 0;
    }
    __syncthreads();
    for (int i = t; i < NBUCK; i += blockDim.x) cnt[i] = 0;  // reuse as cursor
    __syncthreads();
    for (int i = t; i < CHUNK; i += blockDim.x) {
        long long e = base + i;
        if (e >= NNZ) continue;
        int r = rows[e];
        int b = r >> 9;
        int pos = start[b] + atomicAdd(&cnt[b], 1);
        uint64_t packed = ((uint64_t)(uint32_t)__float_as_int(vals[e]) << 32)
                        | ((uint64_t)(r & (RPB - 1)) << 20)
                        | (uint32_t)cols[e];
        edges[pos] = packed;
    }
}

__global__ void k_bucket_sort(const int* __restrict__ bbase, uint64_t* __restrict__ edges,
                              int* __restrict__ row_ptr) {
    __shared__ uint64_t stage[CAP];
    __shared__ int hist[RPB];
    __shared__ int cur[RPB];
    int b = blockIdx.x;
    int t = threadIdx.x;
    int bb = bbase[b];
    int cnt = bbase[b + 1] - bb;
    for (int i = t; i < cnt; i += blockDim.x) stage[i] = edges[bb + i];
    for (int i = t; i < RPB; i += blockDim.x) hist[i] = 0;
    __syncthreads();
    for (int i = t; i < cnt; i += blockDim.x)
        atomicAdd(&hist[(uint32_t)(stage[i] >> 20) & (RPB - 1)], 1);
    __syncthreads();
    for (int off = 1; off < RPB; off <<= 1) {
        int v = (t >= off) ? hist[t - off] : 0;
        __syncthreads();
        hist[t] += v;
        __syncthreads();
    }
    int excl = (t == 0) ? 0 : hist[t - 1];
    long long row = (long long)b * RPB + t;
    if (row < NNODES) row_ptr[row] = bb + excl;
    cur[t] = excl;
    __syncthreads();
    for (int i = t; i < cnt; i += blockDim.x) {
        uint64_t e = stage[i];
        int lr = (uint32_t)(e >> 20) & (RPB - 1);
        int pos = atomicAdd(&cur[lr], 1);
        edges[bb + pos] = (e & 0xFFFFFFFF00000000ull) | (e & 0xFFFFFull);
    }
}

// ---------------- fused pull hop: 8 rows/wave, 4-deep unrolled gather ----------------
// lane = (g=row-in-wave: lane>>3, l=16B slot: lane&7). Each 8-lane group walks
// its own row's edge list, 4 edges per iteration with loads batched before FMAs
// -> up to 32 gather cache lines in flight per wave.
// EPI: 1 = read +ego from bf16 table; 0 = from fp32 inputs (nt).
// dst[r] = (sum_j v_j * src_bf[c_j] + ego(r)) * (FINAL ? 0.25 : 1)

template<int EPI, bool FINAL>
__global__ void k_hop(const int* __restrict__ row_ptr,
                      const uint64_t* __restrict__ edges,
                      const u4* __restrict__ src_bf,
                      const u4* __restrict__ ego_bf,
                      const float* __restrict__ uemb,
                      const float* __restrict__ iemb,
                      void* __restrict__ dst) {
    int wave = (blockIdx.x * blockDim.x + threadIdx.x) >> 6;
    int lane = threadIdx.x & 63;
    int g = lane >> 3;   // row within wave's 8
    int l = lane & 7;    // 16B slot within 128B bf16 row
    int r = wave * 8 + g;
    bool rv = (r < NNODES);
    int beg = rv ? row_ptr[r] : 0;
    int end = rv ? row_ptr[r + 1] : 0;
    float acc0[8], acc1[8];
    #pragma unroll
    for (int k = 0; k < 8; ++k) { acc0[k] = 0.f; acc1[k] = 0.f; }
    for (int j = beg; ; j += 4) {
        if (!__any(j < end)) break;
        uint64_t cv[4];
        bool act[4];
        #pragma unroll
        for (int u = 0; u < 4; ++u) {
            act[u] = (j + u < end);
            if (act[u]) cv[u] = __builtin_nontemporal_load(&edges[j + u]);
        }
        u4 s[4];
        #pragma unroll
        for (int u = 0; u < 4; ++u) {
            if (act[u]) s[u] = src_bf[((size_t)((uint32_t)cv[u] & 0xFFFFFu) << 3) + l];
        }
        #pragma unroll
        for (int u = 0; u < 4; ++u) {
            if (act[u]) {
                float v = __int_as_float((int)(cv[u] >> 32));
                float* a = (u & 1) ? acc1 : acc0;
                a[0] += v * bl(s[u].x); a[1] += v * bh(s[u].x);
                a[2] += v * bl(s[u].y); a[3] += v * bh(s[u].y);
                a[4] += v * bl(s[u].z); a[5] += v * bh(s[u].z);
                a[6] += v * bl(s[u].w); a[7] += v * bh(s[u].w);
            }
        }
    }
    if (!rv) return;
    float e[8];
    if (EPI == 1) {
        u4 eg = ego_bf[((size_t)r << 3) + l];
        e[0] = bl(eg.x); e[1] = bh(eg.x); e[2] = bl(eg.y); e[3] = bh(eg.y);
        e[4] = bl(eg.z); e[5] = bh(eg.z); e[6] = bl(eg.w); e[7] = bh(eg.w);
    } else {
        const f4* ep = (r < NUM_USER)
            ? (const f4*)uemb + ((size_t)r << 4) + l * 2
            : (const f4*)iemb + ((size_t)(r - NUM_USER) << 4) + l * 2;
        f4 e0 = __builtin_nontemporal_load(ep);
        f4 e1 = __builtin_nontemporal_load(ep + 1);
        e[0] = e0.x; e[1] = e0.y; e[2] = e0.z; e[3] = e0.w;
        e[4] = e1.x; e[5] = e1.y; e[6] = e1.z; e[7] = e1.w;
    }
    float res[8];
    #pragma unroll
    for (int k = 0; k < 8; ++k) res[k] = acc0[k] + acc1[k] + e[k];
    if (FINAL) {
        f4 o0 = {res[0] * 0.25f, res[1] * 0.25f, res[2] * 0.25f, res[3] * 0.25f};
        f4 o1 = {res[4] * 0.25f, res[5] * 0.25f, res[6] * 0.25f, res[7] * 0.25f};
        f4* dp = (f4*)dst + ((size_t)r << 4) + l * 2;
        __builtin_nontemporal_store(o0, dp);
        __builtin_nontemporal_store(o1, dp + 1);
    } else {
        u4 o;
        o.x = pack2(res[0], res[1]); o.y = pack2(res[2], res[3]);
        o.z = pack2(res[4], res[5]); o.w = pack2(res[6], res[7]);
        __builtin_nontemporal_store(o, (u4*)dst + ((size_t)r << 3) + l);
    }
}

extern "C" void kernel_launch(void* const* d_in, const int* in_sizes, int n_in,
                              void* d_out, int out_size, void* d_ws, size_t ws_size,
                              hipStream_t stream) {
    const float* vals = (const float*)d_in[0];
    const float* uemb = (const float*)d_in[1];
    const float* iemb = (const float*)d_in[2];
    const int*   rows = (const int*)d_in[3];
    const int*   cols = rows + NNZ;

    float* out = (float*)d_out;

    // ---- workspace layout ----
    size_t off = 0;
    char* ws = (char*)d_ws;
    auto take = [&](size_t bytes) { char* p = ws + off; off += (bytes + 255) & ~(size_t)255; return p; };
    u4*       ego_bf  = (u4*)take((ND / 8) * sizeof(u4));   // 76.8 MB
    u4*       X1      = (u4*)take((ND / 8) * sizeof(u4));   // 76.8 MB
    int*      row_ptr = (int*)take((NNODES + 1) * sizeof(int));
    int*      bcnt    = (int*)take(NBUCK * sizeof(int));
    int*      bbase   = (int*)take((NBUCK + 1) * sizeof(int));
    int*      bcur    = (int*)take(NBUCK * sizeof(int));
    uint64_t* edges   = (uint64_t*)take((size_t)NNZ * sizeof(uint64_t));  // 48 MB
    u4*       X2      = (u4*)take((ND / 8) * sizeof(u4));    // +76.8 MB (conditional)
    bool three_buf = (off <= ws_size);

    // ---- ego -> bf16 table ----
    const long long cvt_threads = ND / 8;
    k_cvt<<<(int)((cvt_threads + 255) / 256), 256, 0, stream>>>(uemb, iemb, ego_bf);

    // ---- build row-sorted edge list ----
    hipMemsetAsync(bcnt, 0, NBUCK * sizeof(int), stream);
    k_coarse_hist<<<512, 512, 0, stream>>>(rows, bcnt);
    k_bucket_scan<<<1, 1024, 0, stream>>>(bcnt, bbase, bcur, row_ptr);
    k_coarse_scatter<<<(NNZ + CHUNK - 1) / CHUNK, 512, 0, stream>>>(rows, cols, vals, bcur, edges);
    k_bucket_sort<<<NBUCK, RPB, 0, stream>>>(bbase, edges, row_ptr);

    // ---- 3 fused hops (Horner): X1 = Ae+e; X2 = A X1+e; out = (A X2+e)/4 ----
    const int hop_blocks = (NNODES + 31) / 32;   // 8 rows/wave, 4 waves/block
    if (three_buf) {
        k_hop<1, false><<<hop_blocks, 256, 0, stream>>>(row_ptr, edges, ego_bf, ego_bf, uemb, iemb, X1);
        k_hop<1, false><<<hop_blocks, 256, 0, stream>>>(row_ptr, edges, X1,     ego_bf, uemb, iemb, X2);
        k_hop<1, true ><<<hop_blocks, 256, 0, stream>>>(row_ptr, edges, X2,     ego_bf, uemb, iemb, out);
    } else {
        // 2-buffer fallback: hop2 writes over ego_bf (safe: its epilogue reads fp32),
        // hops 2-3 read +ego from fp32 inputs with nt loads.
        k_hop<1, false><<<hop_blocks, 256, 0, stream>>>(row_ptr, edges, ego_bf, ego_bf, uemb, iemb, X1);
        k_hop<0, false><<<hop_blocks, 256, 0, stream>>>(row_ptr, edges, X1,     nullptr, uemb, iemb, ego_bf);
        k_hop<0, true ><<<hop_blocks, 256, 0, stream>>>(row_ptr, edges, ego_bf, nullptr, uemb, iemb, out);
    }
}

// Round 9
// 723.555 us; speedup vs baseline: 6.0596x; 1.0119x over previous
//
#include <hip/hip_runtime.h>
#include <stdint.h>

#define NUM_USER 200000
#define NUM_ITEM 400000
#define NNODES   (NUM_USER + NUM_ITEM)   // 600000
#define D        64
#define NNZ      6000000
#define ND       ((size_t)NNODES * D)    // 38.4e6 elements

#define RPB       512                     // rows per bucket
#define NBUCK     ((NNODES + RPB - 1) / RPB)   // 1172
#define CAP       8192                    // max edges staged per bucket (mean 5119)
#define CHUNK     16384                   // edges per block in coarse scatter

typedef float    f4 __attribute__((ext_vector_type(4)));
typedef uint32_t u4 __attribute__((ext_vector_type(4)));

// ---- bf16 helpers (RNE) ----
__device__ __forceinline__ uint32_t bfr(float f) {
    uint32_t u = __float_as_uint(f);
    return (u + 0x7FFFu + ((u >> 16) & 1u)) >> 16;
}
__device__ __forceinline__ uint32_t pack2(float lo, float hi) {
    return (bfr(hi) << 16) | bfr(lo);
}
__device__ __forceinline__ float bl(uint32_t u) { return __uint_as_float(u << 16); }
__device__ __forceinline__ float bh(uint32_t u) { return __uint_as_float(u & 0xFFFF0000u); }

// ---------------- ego -> bf16 table (one pass) ----------------
__global__ void k_cvt(const float* __restrict__ uemb, const float* __restrict__ iemb,
                      u4* __restrict__ ego_bf) {
    long long tid = (long long)blockIdx.x * blockDim.x + threadIdx.x;
    if (tid >= (long long)(ND / 8)) return;
    int node = (int)(tid >> 3);
    int seg = (int)(tid & 7);
    const f4* src = (node < NUM_USER)
        ? (const f4*)uemb + ((size_t)node << 4) + seg * 2
        : (const f4*)iemb + ((size_t)(node - NUM_USER) << 4) + seg * 2;
    f4 a = src[0], b = src[1];
    u4 o;
    o.x = pack2(a.x, a.y); o.y = pack2(a.z, a.w);
    o.z = pack2(b.x, b.y); o.w = pack2(b.z, b.w);
    ego_bf[tid] = o;
}

// ---------------- CSR build: two-level bucket multisplit ----------------

__global__ void k_coarse_hist(const int* __restrict__ rows, int* __restrict__ bcnt) {
    __shared__ int h[NBUCK];
    for (int i = threadIdx.x; i < NBUCK; i += blockDim.x) h[i] = 0;
    __syncthreads();
    int stride = gridDim.x * blockDim.x;
    for (int e = blockIdx.x * blockDim.x + threadIdx.x; e < NNZ; e += stride)
        atomicAdd(&h[rows[e] >> 9], 1);
    __syncthreads();
    for (int i = threadIdx.x; i < NBUCK; i += blockDim.x)
        if (h[i]) atomicAdd(&bcnt[i], h[i]);
}

__global__ void k_bucket_scan(const int* __restrict__ bcnt, int* __restrict__ bbase,
                              int* __restrict__ bcur, int* __restrict__ row_ptr) {
    __shared__ int tsum[1024];
    int t = threadIdx.x;
    int i0 = 2 * t, i1 = 2 * t + 1;
    int c0 = (i0 < NBUCK) ? bcnt[i0] : 0;
    int c1 = (i1 < NBUCK) ? bcnt[i1] : 0;
    tsum[t] = c0 + c1;
    __syncthreads();
    for (int off = 1; off < 1024; off <<= 1) {
        int v = (t >= off) ? tsum[t - off] : 0;
        __syncthreads();
        tsum[t] += v;
        __syncthreads();
    }
    int excl = (t == 0) ? 0 : tsum[t - 1];
    if (i0 < NBUCK) { bbase[i0] = excl;      bcur[i0] = excl; }
    if (i1 < NBUCK) { bbase[i1] = excl + c0; bcur[i1] = excl + c0; }
    if (t == 0) { bbase[NBUCK] = NNZ; row_ptr[NNODES] = NNZ; }
}

__global__ void k_coarse_scatter(const int* __restrict__ rows, const int* __restrict__ cols,
                                 const float* __restrict__ vals, int* __restrict__ bcur,
                                 uint64_t* __restrict__ edges) {
    __shared__ int cnt[NBUCK];
    __shared__ int start[NBUCK];
    int t = threadIdx.x;
    long long base = (long long)blockIdx.x * CHUNK;
    for (int i = t; i < NBUCK; i += blockDim.x) cnt[i] = 0;
    __syncthreads();
    for (int i = t; i < CHUNK; i += blockDim.x) {
        long long e = base + i;
        if (e < NNZ) atomicAdd(&cnt[rows[e] >> 9], 1);
    }
    __syncthreads();
    for (int b = t; b < NBUCK; b += blockDim.x) {
        int c = cnt[b];
        start[b] = c ? atomicAdd(&bcur[b], c) : 0;
    }
    __syncthreads();
    for (int i = t; i < NBUCK; i += blockDim.x) cnt[i] = 0;  // reuse as cursor
    __syncthreads();
    for (int i = t; i < CHUNK; i += blockDim.x) {
        long long e = base + i;
        if (e >= NNZ) continue;
        int r = rows[e];
        int b = r >> 9;
        int pos = start[b] + atomicAdd(&cnt[b], 1);
        uint64_t packed = ((uint64_t)(uint32_t)__float_as_int(vals[e]) << 32)
                        | ((uint64_t)(r & (RPB - 1)) << 20)
                        | (uint32_t)cols[e];
        edges[pos] = packed;
    }
}

__global__ void k_bucket_sort(const int* __restrict__ bbase, uint64_t* __restrict__ edges,
                              int* __restrict__ row_ptr) {
    __shared__ uint64_t stage[CAP];
    __shared__ int hist[RPB];
    __shared__ int cur[RPB];
    int b = blockIdx.x;
    int t = threadIdx.x;
    int bb = bbase[b];
    int cnt = bbase[b + 1] - bb;
    for (int i = t; i < cnt; i += blockDim.x) stage[i] = edges[bb + i];
    for (int i = t; i < RPB; i += blockDim.x) hist[i] = 0;
    __syncthreads();
    for (int i = t; i < cnt; i += blockDim.x)
        atomicAdd(&hist[(uint32_t)(stage[i] >> 20) & (RPB - 1)], 1);
    __syncthreads();
    for (int off = 1; off < RPB; off <<= 1) {
        int v = (t >= off) ? hist[t - off] : 0;
        __syncthreads();
        hist[t] += v;
        __syncthreads();
    }
    int excl = (t == 0) ? 0 : hist[t - 1];
    long long row = (long long)b * RPB + t;
    if (row < NNODES) row_ptr[row] = bb + excl;
    cur[t] = excl;
    __syncthreads();
    for (int i = t; i < cnt; i += blockDim.x) {
        uint64_t e = stage[i];
        int lr = (uint32_t)(e >> 20) & (RPB - 1);
        int pos = atomicAdd(&cur[lr], 1);
        edges[bb + pos] = (e & 0xFFFFFFFF00000000ull) | (e & 0xFFFFFull);
    }
}

// ---------------- fused pull hop: 8 rows/wave, 8-deep unrolled gather ----------------
// lane = (g=row-in-wave: lane>>3, l=16B slot: lane&7). Each 8-lane group walks
// its own row's edge list, 8 edges per iteration with loads batched before FMAs
// -> up to 64 gather cache lines in flight per wave.
// Edges and bf16 stores are CACHED (LLC-resident for the next hop); only the
// final fp32 out store is non-temporal.
// dst[r] = (sum_j v_j * src_bf[c_j] + ego(r)) * (FINAL ? 0.25 : 1)

template<int EPI, bool FINAL>
__global__ void k_hop(const int* __restrict__ row_ptr,
                      const uint64_t* __restrict__ edges,
                      const u4* __restrict__ src_bf,
                      const u4* __restrict__ ego_bf,
                      const float* __restrict__ uemb,
                      const float* __restrict__ iemb,
                      void* __restrict__ dst) {
    constexpr int U = 8;
    int wave = (blockIdx.x * blockDim.x + threadIdx.x) >> 6;
    int lane = threadIdx.x & 63;
    int g = lane >> 3;   // row within wave's 8
    int l = lane & 7;    // 16B slot within 128B bf16 row
    int r = wave * 8 + g;
    bool rv = (r < NNODES);
    int beg = rv ? row_ptr[r] : 0;
    int end = rv ? row_ptr[r + 1] : 0;
    float acc0[8], acc1[8];
    #pragma unroll
    for (int k = 0; k < 8; ++k) { acc0[k] = 0.f; acc1[k] = 0.f; }
    for (int j = beg; ; j += U) {
        if (!__any(j < end)) break;
        uint64_t cv[U];
        bool act[U];
        #pragma unroll
        for (int u = 0; u < U; ++u) {
            act[u] = (j + u < end);
            if (act[u]) cv[u] = edges[j + u];
        }
        u4 s[U];
        #pragma unroll
        for (int u = 0; u < U; ++u) {
            if (act[u]) s[u] = src_bf[((size_t)((uint32_t)cv[u] & 0xFFFFFu) << 3) + l];
        }
        #pragma unroll
        for (int u = 0; u < U; ++u) {
            if (act[u]) {
                float v = __int_as_float((int)(cv[u] >> 32));
                float* a = (u & 1) ? acc1 : acc0;
                a[0] += v * bl(s[u].x); a[1] += v * bh(s[u].x);
                a[2] += v * bl(s[u].y); a[3] += v * bh(s[u].y);
                a[4] += v * bl(s[u].z); a[5] += v * bh(s[u].z);
                a[6] += v * bl(s[u].w); a[7] += v * bh(s[u].w);
            }
        }
    }
    if (!rv) return;
    float e[8];
    if (EPI == 1) {
        u4 eg = ego_bf[((size_t)r << 3) + l];
        e[0] = bl(eg.x); e[1] = bh(eg.x); e[2] = bl(eg.y); e[3] = bh(eg.y);
        e[4] = bl(eg.z); e[5] = bh(eg.z); e[6] = bl(eg.w); e[7] = bh(eg.w);
    } else {
        const f4* ep = (r < NUM_USER)
            ? (const f4*)uemb + ((size_t)r << 4) + l * 2
            : (const f4*)iemb + ((size_t)(r - NUM_USER) << 4) + l * 2;
        f4 e0 = ep[0], e1 = ep[1];
        e[0] = e0.x; e[1] = e0.y; e[2] = e0.z; e[3] = e0.w;
        e[4] = e1.x; e[5] = e1.y; e[6] = e1.z; e[7] = e1.w;
    }
    float res[8];
    #pragma unroll
    for (int k = 0; k < 8; ++k) res[k] = acc0[k] + acc1[k] + e[k];
    if (FINAL) {
        f4 o0 = {res[0] * 0.25f, res[1] * 0.25f, res[2] * 0.25f, res[3] * 0.25f};
        f4 o1 = {res[4] * 0.25f, res[5] * 0.25f, res[6] * 0.25f, res[7] * 0.25f};
        f4* dp = (f4*)dst + ((size_t)r << 4) + l * 2;
        __builtin_nontemporal_store(o0, dp);
        __builtin_nontemporal_store(o1, dp + 1);
    } else {
        u4 o;
        o.x = pack2(res[0], res[1]); o.y = pack2(res[2], res[3]);
        o.z = pack2(res[4], res[5]); o.w = pack2(res[6], res[7]);
        *((u4*)dst + ((size_t)r << 3) + l) = o;   // cached: next hop gathers this
    }
}

extern "C" void kernel_launch(void* const* d_in, const int* in_sizes, int n_in,
                              void* d_out, int out_size, void* d_ws, size_t ws_size,
                              hipStream_t stream) {
    const float* vals = (const float*)d_in[0];
    const float* uemb = (const float*)d_in[1];
    const float* iemb = (const float*)d_in[2];
    const int*   rows = (const int*)d_in[3];
    const int*   cols = rows + NNZ;

    float* out = (float*)d_out;

    // ---- workspace layout ----
    size_t off = 0;
    char* ws = (char*)d_ws;
    auto take = [&](size_t bytes) { char* p = ws + off; off += (bytes + 255) & ~(size_t)255; return p; };
    u4*       ego_bf  = (u4*)take((ND / 8) * sizeof(u4));   // 76.8 MB
    u4*       X1      = (u4*)take((ND / 8) * sizeof(u4));   // 76.8 MB
    int*      row_ptr = (int*)take((NNODES + 1) * sizeof(int));
    int*      bcnt    = (int*)take(NBUCK * sizeof(int));
    int*      bbase   = (int*)take((NBUCK + 1) * sizeof(int));
    int*      bcur    = (int*)take(NBUCK * sizeof(int));
    uint64_t* edges   = (uint64_t*)take((size_t)NNZ * sizeof(uint64_t));  // 48 MB
    u4*       X2      = (u4*)take((ND / 8) * sizeof(u4));    // +76.8 MB (conditional)
    bool three_buf = (off <= ws_size);

    // ---- ego -> bf16 table ----
    const long long cvt_threads = ND / 8;
    k_cvt<<<(int)((cvt_threads + 255) / 256), 256, 0, stream>>>(uemb, iemb, ego_bf);

    // ---- build row-sorted edge list ----
    hipMemsetAsync(bcnt, 0, NBUCK * sizeof(int), stream);
    k_coarse_hist<<<512, 512, 0, stream>>>(rows, bcnt);
    k_bucket_scan<<<1, 1024, 0, stream>>>(bcnt, bbase, bcur, row_ptr);
    k_coarse_scatter<<<(NNZ + CHUNK - 1) / CHUNK, 512, 0, stream>>>(rows, cols, vals, bcur, edges);
    k_bucket_sort<<<NBUCK, RPB, 0, stream>>>(bbase, edges, row_ptr);

    // ---- 3 fused hops (Horner): X1 = Ae+e; X2 = A X1+e; out = (A X2+e)/4 ----
    const int hop_blocks = (NNODES + 31) / 32;   // 8 rows/wave, 4 waves/block
    if (three_buf) {
        k_hop<1, false><<<hop_blocks, 256, 0, stream>>>(row_ptr, edges, ego_bf, ego_bf, uemb, iemb, X1);
        k_hop<1, false><<<hop_blocks, 256, 0, stream>>>(row_ptr, edges, X1,     ego_bf, uemb, iemb, X2);
        k_hop<1, true ><<<hop_blocks, 256, 0, stream>>>(row_ptr, edges, X2,     ego_bf, uemb, iemb, out);
    } else {
        // 2-buffer fallback: hop2 writes over ego_bf (safe: its epilogue reads fp32),
        // hops 2-3 read +ego from fp32 inputs.
        k_hop<1, false><<<hop_blocks, 256, 0, stream>>>(row_ptr, edges, ego_bf, ego_bf, uemb, iemb, X1);
        k_hop<0, false><<<hop_blocks, 256, 0, stream>>>(row_ptr, edges, X1,     nullptr, uemb, iemb, ego_bf);
        k_hop<0, true ><<<hop_blocks, 256, 0, stream>>>(row_ptr, edges, ego_bf, nullptr, uemb, iemb, out);
    }
}